// Round 8
// baseline (1496.188 us; speedup 1.0000x reference)
//
#include <hip/hip_runtime.h>

#define SEQ 4096
#define BATCH 512
#define INP 8
#define HID 30
#define LOG2E 1.44269504088896340736f

typedef float f32x2 __attribute__((ext_vector_type(2)));
typedef float f32x4 __attribute__((ext_vector_type(4)));
typedef unsigned uint2v __attribute__((ext_vector_type(2)));

#define RCP(v)  __builtin_amdgcn_rcpf(v)
#if __has_builtin(__builtin_amdgcn_exp2f)
#define EXP2(v) __builtin_amdgcn_exp2f(v)
#else
#define EXP2(v) exp2f(v)
#endif
#define PKFMA(a, b, c) __builtin_elementwise_fma(a, b, c)

// permlane32_swap with both operands = v:
//   returns {lo_rep = [v_lo32 | v_lo32], hi_rep = [v_hi32 | v_hi32]}
__device__ __forceinline__ void rep_halves(float v, float& lo_rep, float& hi_rep) {
#if __has_builtin(__builtin_amdgcn_permlane32_swap)
    uint2v r = __builtin_amdgcn_permlane32_swap(
        __float_as_uint(v), __float_as_uint(v), false, false);
    lo_rep = __uint_as_float(r.x);
    hi_rep = __uint_as_float(r.y);
#else
    float other = __shfl_xor(v, 32, 64);
    bool hi = (threadIdx.x & 32) != 0;
    lo_rep = hi ? other : v;
    hi_rep = hi ? v : other;
#endif
}

template <int CTRL>
__device__ __forceinline__ float dpp_sum_step(float v) {
    return v + __uint_as_float(__builtin_amdgcn_update_dpp(
        0, (int)__float_as_uint(v), CTRL, 0xf, 0xf, true));
}

// Sum within each 32-lane group, pure VALU (no LDS / lgkmcnt stalls).
// Full 32-sum valid in lanes 15,31 (and 47,63).
__device__ __forceinline__ float group32_reduce(float v) {
    v = dpp_sum_step<0x111>(v);  // row_shr:1
    v = dpp_sum_step<0x112>(v);  // row_shr:2
    v = dpp_sum_step<0x114>(v);  // row_shr:4
    v = dpp_sum_step<0x118>(v);  // row_shr:8 -> lane15=sum(0..15), lane31=sum(16..31)
#if __has_builtin(__builtin_amdgcn_permlane16_swap)
    uint2v r = __builtin_amdgcn_permlane16_swap(
        __float_as_uint(v), __float_as_uint(v), false, false);
    return __uint_as_float(r.x) + __uint_as_float(r.y);
#else
    return v + __shfl_xor(v, 16, 64);
#endif
}

// One wave per batch chain (512 waves). y buffered in LDS, dumped at the end
// (K-loop vmcnt queue stays loads-only). h broadcast via LDS round trip
// (stride-1 ds_write, 8x uniform-address ds_read_b128 -> f32x2 pairs) feeding
// v_pk_fma_f32 packed matvec. x prefetched 8 steps ahead (static rotation).
// hh matvec uses 4 accumulator chains per gate side (dep depth 4, not 8).
__global__ __launch_bounds__(64)
__attribute__((amdgpu_waves_per_eu(1, 1)))
void lstm_chain_kernel(
    const float* __restrict__ x,     // [SEQ,BATCH,INP]
    const float* __restrict__ W_ih,  // [4H, INP]
    const float* __restrict__ W_hh,  // [4H, HID]
    const float* __restrict__ b_ih,  // [4H]
    const float* __restrict__ b_hh,  // [4H]
    const float* __restrict__ W_lin, // [1, HID]
    const float* __restrict__ b_lin, // [1]
    float* __restrict__ out)         // [SEQ,BATCH,1]
{
    const int lane = threadIdx.x;
    // XCD-aware swizzle: consecutive chains (sharing 64B x-lines and 32B
    // out-sectors) land on the same XCD's L2.
    const int g    = blockIdx.x;
    const int b    = (g & 7) * (BATCH / 8) + (g >> 3);
    const int j    = lane & 31;
    const int half = lane >> 5;
    const int jc   = j < HID ? j : HID - 1;
    const int ra   = half * HID + jc;            // i (half0) / f (half1): sigmoid
    const int rb   = 2 * HID + half * HID + jc;  // g (half0, tanh) / o (half1, sigmoid)

    // exp2 folding: sigmoid(v)=rcp(1+2^(-log2e*v)); tanh(v)=1-2*rcp(1+2^(2*log2e*v))
    const float sA   = -LOG2E;
    const float sB   = half ? -LOG2E : 2.0f * LOG2E;
    const float sclB = half ? 1.0f : -2.0f;
    const float addB = half ? 0.0f : 1.0f;
    const float T2L  = 2.0f * LOG2E;  // for tanh(c)

    // ---- packed per-lane weights, pre-scaled, pinned in VGPR pairs ----
    f32x2 wih2_a[INP / 2], wih2_b[INP / 2];
#pragma unroll
    for (int i = 0; i < INP / 2; ++i) {
        f32x2 wa = { W_ih[ra * INP + 2 * i] * sA, W_ih[ra * INP + 2 * i + 1] * sA };
        f32x2 wb = { W_ih[rb * INP + 2 * i] * sB, W_ih[rb * INP + 2 * i + 1] * sB };
        asm volatile("" : "+v"(wa));
        asm volatile("" : "+v"(wb));
        wih2_a[i] = wa;
        wih2_b[i] = wb;
    }
    f32x2 whh2_a[HID / 2], whh2_b[HID / 2];
#pragma unroll
    for (int k = 0; k < HID / 2; ++k) {
        f32x2 wa = { W_hh[ra * HID + 2 * k] * sA, W_hh[ra * HID + 2 * k + 1] * sA };
        f32x2 wb = { W_hh[rb * HID + 2 * k] * sB, W_hh[rb * HID + 2 * k + 1] * sB };
        asm volatile("" : "+v"(wa));
        asm volatile("" : "+v"(wb));
        whh2_a[k] = wa;
        whh2_b[k] = wb;
    }
    const float bias_sa = (b_ih[ra] + b_hh[ra]) * sA;
    const float bias_sb = (b_ih[rb] + b_hh[rb]) * sB;
    const float blin    = b_lin[0];
    const float wlin    = (j < HID) ? W_lin[j] : 0.0f;

    __shared__ float s_y[SEQ];
    __shared__ __align__(16) float s_h[64];  // 0..29 valid; 30..63 dup/pad

    f32x2 hrf2[HID / 2];
#pragma unroll
    for (int k = 0; k < HID / 2; ++k) hrf2[k] = (f32x2){0.0f, 0.0f};
    float c = 0.0f;

#define LOADX(XA, XB, TL) do {                                                \
    int _tl = (TL) < SEQ ? (TL) : SEQ - 1;                                    \
    const f32x4* _xp = (const f32x4*)(x + ((size_t)_tl * BATCH + b) * INP);   \
    XA = _xp[0]; XB = _xp[1];                                                 \
} while (0)

    f32x4 xA0, xB0, xA1, xB1, xA2, xB2, xA3, xB3;
    f32x4 xA4, xB4, xA5, xB5, xA6, xB6, xA7, xB7;
    LOADX(xA0, xB0, 0);  LOADX(xA1, xB1, 1);
    LOADX(xA2, xB2, 2);  LOADX(xA3, xB3, 3);
    LOADX(xA4, xB4, 4);  LOADX(xA5, xB5, 5);
    LOADX(xA6, xB6, 6);  LOADX(xA7, xB7, 7);

    const f32x4* s_h4 = reinterpret_cast<const f32x4*>(s_h);

#define STEP(T, XA, XB) do {                                                  \
    f32x2 A0 = {bias_sa, 0.0f}, B0 = {bias_sb, 0.0f};                         \
    f32x2 A1 = {0.0f, 0.0f},    B1 = {0.0f, 0.0f};                            \
    f32x2 A2 = {0.0f, 0.0f},    B2 = {0.0f, 0.0f};                            \
    f32x2 A3 = {0.0f, 0.0f},    B3 = {0.0f, 0.0f};                            \
    f32x2 x01 = __builtin_shufflevector(XA, XA, 0, 1);                        \
    f32x2 x23 = __builtin_shufflevector(XA, XA, 2, 3);                        \
    f32x2 x45 = __builtin_shufflevector(XB, XB, 0, 1);                        \
    f32x2 x67 = __builtin_shufflevector(XB, XB, 2, 3);                        \
    A0 = PKFMA(x01, wih2_a[0], A0);  B0 = PKFMA(x01, wih2_b[0], B0);          \
    A1 = PKFMA(x23, wih2_a[1], A1);  B1 = PKFMA(x23, wih2_b[1], B1);          \
    A2 = PKFMA(x45, wih2_a[2], A2);  B2 = PKFMA(x45, wih2_b[2], B2);          \
    A3 = PKFMA(x67, wih2_a[3], A3);  B3 = PKFMA(x67, wih2_b[3], B3);          \
    _Pragma("unroll")                                                         \
    for (int k = 0; k < 12; k += 4) {                                         \
        A0 = PKFMA(hrf2[k],   whh2_a[k],   A0);                               \
        B0 = PKFMA(hrf2[k],   whh2_b[k],   B0);                               \
        A1 = PKFMA(hrf2[k+1], whh2_a[k+1], A1);                               \
        B1 = PKFMA(hrf2[k+1], whh2_b[k+1], B1);                               \
        A2 = PKFMA(hrf2[k+2], whh2_a[k+2], A2);                               \
        B2 = PKFMA(hrf2[k+2], whh2_b[k+2], B2);                               \
        A3 = PKFMA(hrf2[k+3], whh2_a[k+3], A3);                               \
        B3 = PKFMA(hrf2[k+3], whh2_b[k+3], B3);                               \
    }                                                                         \
    A0 = PKFMA(hrf2[12], whh2_a[12], A0);  B0 = PKFMA(hrf2[12], whh2_b[12], B0); \
    A1 = PKFMA(hrf2[13], whh2_a[13], A1);  B1 = PKFMA(hrf2[13], whh2_b[13], B1); \
    A2 = PKFMA(hrf2[14], whh2_a[14], A2);  B2 = PKFMA(hrf2[14], whh2_b[14], B2); \
    f32x2 As = (A0 + A1) + (A2 + A3);                                         \
    f32x2 Bs = (B0 + B1) + (B2 + B3);                                         \
    float ua = As.x + As.y;                                                   \
    float ub = Bs.x + Bs.y;                                                   \
    float Av  = RCP(1.0f + EXP2(ua));                                         \
    float sBv = RCP(1.0f + EXP2(ub));                                         \
    float Bv  = fmaf(sBv, sclB, addB);                                        \
    float ii, ff, gg, oo;                                                     \
    rep_halves(Av, ii, ff);                                                   \
    rep_halves(Bv, gg, oo);                                                   \
    c = fmaf(ff, c, ii * gg);                                                 \
    float sc = RCP(1.0f + EXP2(c * T2L));                                     \
    float h  = oo * fmaf(sc, -2.0f, 1.0f);                                    \
    s_h[lane] = h;  /* all lanes write; lane 32+j duplicates h_j */           \
    float p = group32_reduce(h * wlin);                                       \
    if (lane == 31) s_y[T] = p + blin;                                        \
    f32x4 hv0 = s_h4[0], hv1 = s_h4[1], hv2 = s_h4[2], hv3 = s_h4[3];         \
    f32x4 hv4 = s_h4[4], hv5 = s_h4[5], hv6 = s_h4[6], hv7 = s_h4[7];         \
    hrf2[0]  = __builtin_shufflevector(hv0, hv0, 0, 1);                       \
    hrf2[1]  = __builtin_shufflevector(hv0, hv0, 2, 3);                       \
    hrf2[2]  = __builtin_shufflevector(hv1, hv1, 0, 1);                       \
    hrf2[3]  = __builtin_shufflevector(hv1, hv1, 2, 3);                       \
    hrf2[4]  = __builtin_shufflevector(hv2, hv2, 0, 1);                       \
    hrf2[5]  = __builtin_shufflevector(hv2, hv2, 2, 3);                       \
    hrf2[6]  = __builtin_shufflevector(hv3, hv3, 0, 1);                       \
    hrf2[7]  = __builtin_shufflevector(hv3, hv3, 2, 3);                       \
    hrf2[8]  = __builtin_shufflevector(hv4, hv4, 0, 1);                       \
    hrf2[9]  = __builtin_shufflevector(hv4, hv4, 2, 3);                       \
    hrf2[10] = __builtin_shufflevector(hv5, hv5, 0, 1);                       \
    hrf2[11] = __builtin_shufflevector(hv5, hv5, 2, 3);                       \
    hrf2[12] = __builtin_shufflevector(hv6, hv6, 0, 1);                       \
    hrf2[13] = __builtin_shufflevector(hv6, hv6, 2, 3);                       \
    hrf2[14] = __builtin_shufflevector(hv7, hv7, 0, 1);                       \
} while (0)

    for (int t = 0; t < SEQ; t += 8) {
        STEP(t + 0, xA0, xB0);  LOADX(xA0, xB0, t + 8);
        STEP(t + 1, xA1, xB1);  LOADX(xA1, xB1, t + 9);
        STEP(t + 2, xA2, xB2);  LOADX(xA2, xB2, t + 10);
        STEP(t + 3, xA3, xB3);  LOADX(xA3, xB3, t + 11);
        STEP(t + 4, xA4, xB4);  LOADX(xA4, xB4, t + 12);
        STEP(t + 5, xA5, xB5);  LOADX(xA5, xB5, t + 13);
        STEP(t + 6, xA6, xB6);  LOADX(xA6, xB6, t + 14);
        STEP(t + 7, xA7, xB7);  LOADX(xA7, xB7, t + 15);
    }
#undef STEP
#undef LOADX

    // ---- dump y: 4096 floats, 16 iterations of (ds_read_b128 + 4 stores) ----
    __syncthreads();  // single wave; orders the last ds_write before reads
    const float4* s_y4 = reinterpret_cast<const float4*>(s_y);
#pragma unroll 4
    for (int it = 0; it < SEQ / 256; ++it) {
        int tbase = it * 256 + lane * 4;
        float4 v = s_y4[tbase >> 2];
        out[(size_t)(tbase + 0) * BATCH + b] = v.x;
        out[(size_t)(tbase + 1) * BATCH + b] = v.y;
        out[(size_t)(tbase + 2) * BATCH + b] = v.z;
        out[(size_t)(tbase + 3) * BATCH + b] = v.w;
    }
}

extern "C" void kernel_launch(void* const* d_in, const int* in_sizes, int n_in,
                              void* d_out, int out_size, void* d_ws, size_t ws_size,
                              hipStream_t stream) {
    const float* x     = (const float*)d_in[0];
    const float* W_ih  = (const float*)d_in[1];
    const float* W_hh  = (const float*)d_in[2];
    const float* b_ih  = (const float*)d_in[3];
    const float* b_hh  = (const float*)d_in[4];
    const float* W_lin = (const float*)d_in[5];
    const float* b_lin = (const float*)d_in[6];
    float* out = (float*)d_out;

    lstm_chain_kernel<<<dim3(BATCH), dim3(64), 0, stream>>>(
        x, W_ih, W_hh, b_ih, b_hh, W_lin, b_lin, out);
}

// Round 9
// 1492.214 us; speedup vs baseline: 1.0027x; 1.0027x over previous
//
#include <hip/hip_runtime.h>

#define SEQ 4096
#define BATCH 512
#define INP 8
#define HID 30
#define LOG2E 1.44269504088896340736f

typedef float f32x2 __attribute__((ext_vector_type(2)));
typedef float f32x4 __attribute__((ext_vector_type(4)));
typedef unsigned uint2v __attribute__((ext_vector_type(2)));

#define RCP(v)  __builtin_amdgcn_rcpf(v)
#if __has_builtin(__builtin_amdgcn_exp2f)
#define EXP2(v) __builtin_amdgcn_exp2f(v)
#else
#define EXP2(v) exp2f(v)
#endif
#define PKFMA(a, b, c) __builtin_elementwise_fma(a, b, c)

// permlane32_swap with both operands = v:
//   returns {lo_rep = [v_lo32 | v_lo32], hi_rep = [v_hi32 | v_hi32]}
__device__ __forceinline__ void rep_halves(float v, float& lo_rep, float& hi_rep) {
#if __has_builtin(__builtin_amdgcn_permlane32_swap)
    uint2v r = __builtin_amdgcn_permlane32_swap(
        __float_as_uint(v), __float_as_uint(v), false, false);
    lo_rep = __uint_as_float(r.x);
    hi_rep = __uint_as_float(r.y);
#else
    float other = __shfl_xor(v, 32, 64);
    bool hi = (threadIdx.x & 32) != 0;
    lo_rep = hi ? other : v;
    hi_rep = hi ? v : other;
#endif
}

template <int CTRL>
__device__ __forceinline__ float dpp_sum_step(float v) {
    return v + __uint_as_float(__builtin_amdgcn_update_dpp(
        0, (int)__float_as_uint(v), CTRL, 0xf, 0xf, true));
}

// Sum within each 32-lane group, pure VALU. Total valid in lanes 15,31,47,63.
__device__ __forceinline__ float group32_reduce(float v) {
    v = dpp_sum_step<0x111>(v);  // row_shr:1
    v = dpp_sum_step<0x112>(v);  // row_shr:2
    v = dpp_sum_step<0x114>(v);  // row_shr:4
    v = dpp_sum_step<0x118>(v);  // row_shr:8
#if __has_builtin(__builtin_amdgcn_permlane16_swap)
    uint2v r = __builtin_amdgcn_permlane16_swap(
        __float_as_uint(v), __float_as_uint(v), false, false);
    return __uint_as_float(r.x) + __uint_as_float(r.y);
#else
    return v + __shfl_xor(v, 16, 64);
#endif
}

// One wave per batch chain (512 waves). Waves issue IN ORDER, so the ~130cy
// LDS h-broadcast round trip is hidden by placing independent work (DPP
// reduce, s_y store, x prefetch, NEXT step's ih-matvec into rolling preA/preB
// registers) textually between the ds_read issue and the first hrf2 use.
__global__ __launch_bounds__(64)
__attribute__((amdgpu_waves_per_eu(1, 1)))
void lstm_chain_kernel(
    const float* __restrict__ x,     // [SEQ,BATCH,INP]
    const float* __restrict__ W_ih,  // [4H, INP]
    const float* __restrict__ W_hh,  // [4H, HID]
    const float* __restrict__ b_ih,  // [4H]
    const float* __restrict__ b_hh,  // [4H]
    const float* __restrict__ W_lin, // [1, HID]
    const float* __restrict__ b_lin, // [1]
    float* __restrict__ out)         // [SEQ,BATCH,1]
{
    const int lane = threadIdx.x;
    // XCD-aware swizzle: consecutive chains share 64B x-lines / 32B out
    // sectors on one XCD's L2.
    const int g    = blockIdx.x;
    const int b    = (g & 7) * (BATCH / 8) + (g >> 3);
    const int j    = lane & 31;
    const int half = lane >> 5;
    const int jc   = j < HID ? j : HID - 1;
    const int ra   = half * HID + jc;            // i (half0) / f (half1): sigmoid
    const int rb   = 2 * HID + half * HID + jc;  // g (half0, tanh) / o (half1, sigmoid)

    // exp2 folding: sigmoid(v)=rcp(1+2^(-log2e*v)); tanh(v)=1-2*rcp(1+2^(2*log2e*v))
    const float sA   = -LOG2E;
    const float sB   = half ? -LOG2E : 2.0f * LOG2E;
    const float sclB = half ? 1.0f : -2.0f;
    const float addB = half ? 0.0f : 1.0f;
    const float T2L  = 2.0f * LOG2E;  // for tanh(c)

    // ---- packed per-lane weights, pre-scaled, pinned in VGPR pairs ----
    f32x2 wih2_a[INP / 2], wih2_b[INP / 2];
#pragma unroll
    for (int i = 0; i < INP / 2; ++i) {
        f32x2 wa = { W_ih[ra * INP + 2 * i] * sA, W_ih[ra * INP + 2 * i + 1] * sA };
        f32x2 wb = { W_ih[rb * INP + 2 * i] * sB, W_ih[rb * INP + 2 * i + 1] * sB };
        asm volatile("" : "+v"(wa));
        asm volatile("" : "+v"(wb));
        wih2_a[i] = wa;
        wih2_b[i] = wb;
    }
    f32x2 whh2_a[HID / 2], whh2_b[HID / 2];
#pragma unroll
    for (int k = 0; k < HID / 2; ++k) {
        f32x2 wa = { W_hh[ra * HID + 2 * k] * sA, W_hh[ra * HID + 2 * k + 1] * sA };
        f32x2 wb = { W_hh[rb * HID + 2 * k] * sB, W_hh[rb * HID + 2 * k + 1] * sB };
        asm volatile("" : "+v"(wa));
        asm volatile("" : "+v"(wb));
        whh2_a[k] = wa;
        whh2_b[k] = wb;
    }
    const float bias_sa = (b_ih[ra] + b_hh[ra]) * sA;
    const float bias_sb = (b_ih[rb] + b_hh[rb]) * sB;
    const float blin    = b_lin[0];
    const float wlin    = (j < HID) ? W_lin[j] : 0.0f;

    __shared__ float s_y[SEQ];
    __shared__ __align__(16) float s_h[64];  // 0..29 valid; 30..63 dup/pad

    f32x2 hrf2[HID / 2];
#pragma unroll
    for (int k = 0; k < HID / 2; ++k) hrf2[k] = (f32x2){0.0f, 0.0f};
    float c = 0.0f;

#define LOADX(XA, XB, TL) do {                                                \
    int _tl = (TL) < SEQ ? (TL) : SEQ - 1;                                    \
    const f32x4* _xp = (const f32x4*)(x + ((size_t)_tl * BATCH + b) * INP);   \
    XA = _xp[0]; XB = _xp[1];                                                 \
} while (0)

    // rolling pre-activation (bias + W_ih·x) for the NEXT step
    f32x2 preA0, preA1, preB0, preB1;

#define IHPRE(XA, XB) do {                                                    \
    f32x2 x01 = __builtin_shufflevector(XA, XA, 0, 1);                        \
    f32x2 x23 = __builtin_shufflevector(XA, XA, 2, 3);                        \
    f32x2 x45 = __builtin_shufflevector(XB, XB, 0, 1);                        \
    f32x2 x67 = __builtin_shufflevector(XB, XB, 2, 3);                        \
    preA0 = (f32x2){bias_sa, 0.0f};  preB0 = (f32x2){bias_sb, 0.0f};          \
    preA1 = (f32x2){0.0f, 0.0f};     preB1 = (f32x2){0.0f, 0.0f};             \
    preA0 = PKFMA(x01, wih2_a[0], preA0);  preB0 = PKFMA(x01, wih2_b[0], preB0); \
    preA1 = PKFMA(x23, wih2_a[1], preA1);  preB1 = PKFMA(x23, wih2_b[1], preB1); \
    preA0 = PKFMA(x45, wih2_a[2], preA0);  preB0 = PKFMA(x45, wih2_b[2], preB0); \
    preA1 = PKFMA(x67, wih2_a[3], preA1);  preB1 = PKFMA(x67, wih2_b[3], preB1); \
} while (0)

    f32x4 xA0, xB0, xA1, xB1, xA2, xB2, xA3, xB3;
    LOADX(xA0, xB0, 0);  LOADX(xA1, xB1, 1);
    LOADX(xA2, xB2, 2);  LOADX(xA3, xB3, 3);
    IHPRE(xA0, xB0);  // pre for t=0

    const f32x4* s_h4 = reinterpret_cast<const f32x4*>(s_h);

// STEP(T, XAn: x regs for step T+1 (feeds rolling pre),
//         XAl: x reg slot to reload, TL: its new timestep)
#define STEP(T, XAn, XBn, XAl, XBl, TL) do {                                  \
    f32x2 A0 = preA0, A1 = preA1, B0 = preB0, B1 = preB1;                     \
    _Pragma("unroll")                                                         \
    for (int k = 0; k < HID / 2 - 1; k += 2) {                                \
        A0 = PKFMA(hrf2[k],   whh2_a[k],   A0);                               \
        B0 = PKFMA(hrf2[k],   whh2_b[k],   B0);                               \
        A1 = PKFMA(hrf2[k+1], whh2_a[k+1], A1);                               \
        B1 = PKFMA(hrf2[k+1], whh2_b[k+1], B1);                               \
    }                                                                         \
    A0 = PKFMA(hrf2[HID/2-1], whh2_a[HID/2-1], A0);                           \
    B0 = PKFMA(hrf2[HID/2-1], whh2_b[HID/2-1], B0);                           \
    f32x2 As = A0 + A1;  float ua = As.x + As.y;                              \
    f32x2 Bs = B0 + B1;  float ub = Bs.x + Bs.y;                              \
    float Av  = RCP(1.0f + EXP2(ua));                                         \
    float sBv = RCP(1.0f + EXP2(ub));                                         \
    float Bv  = fmaf(sBv, sclB, addB);                                        \
    float ii, ff, gg, oo;                                                     \
    rep_halves(Av, ii, ff);                                                   \
    rep_halves(Bv, gg, oo);                                                   \
    c = fmaf(ff, c, ii * gg);                                                 \
    float sc = RCP(1.0f + EXP2(c * T2L));                                     \
    float h  = oo * fmaf(sc, -2.0f, 1.0f);                                    \
    s_h[lane] = h;                      /* ds_write */                        \
    f32x4 hv0 = s_h4[0], hv1 = s_h4[1], hv2 = s_h4[2], hv3 = s_h4[3];         \
    f32x4 hv4 = s_h4[4], hv5 = s_h4[5], hv6 = s_h4[6], hv7 = s_h4[7];         \
    /* ---- LDS round-trip shadow: independent work below ---- */             \
    float p = group32_reduce(h * wlin);                                       \
    if (lane == 31) s_y[T] = p + blin;                                        \
    LOADX(XAl, XBl, TL);                                                      \
    IHPRE(XAn, XBn);                                                          \
    /* ---- end shadow; unpack broadcast for next step ---- */                \
    hrf2[0]  = __builtin_shufflevector(hv0, hv0, 0, 1);                       \
    hrf2[1]  = __builtin_shufflevector(hv0, hv0, 2, 3);                       \
    hrf2[2]  = __builtin_shufflevector(hv1, hv1, 0, 1);                       \
    hrf2[3]  = __builtin_shufflevector(hv1, hv1, 2, 3);                       \
    hrf2[4]  = __builtin_shufflevector(hv2, hv2, 0, 1);                       \
    hrf2[5]  = __builtin_shufflevector(hv2, hv2, 2, 3);                       \
    hrf2[6]  = __builtin_shufflevector(hv3, hv3, 0, 1);                       \
    hrf2[7]  = __builtin_shufflevector(hv3, hv3, 2, 3);                       \
    hrf2[8]  = __builtin_shufflevector(hv4, hv4, 0, 1);                       \
    hrf2[9]  = __builtin_shufflevector(hv4, hv4, 2, 3);                       \
    hrf2[10] = __builtin_shufflevector(hv5, hv5, 0, 1);                       \
    hrf2[11] = __builtin_shufflevector(hv5, hv5, 2, 3);                       \
    hrf2[12] = __builtin_shufflevector(hv6, hv6, 0, 1);                       \
    hrf2[13] = __builtin_shufflevector(hv6, hv6, 2, 3);                       \
    hrf2[14] = __builtin_shufflevector(hv7, hv7, 0, 1);                       \
} while (0)

    for (int t = 0; t < SEQ; t += 4) {
        STEP(t + 0, xA1, xB1, xA0, xB0, t + 4);
        STEP(t + 1, xA2, xB2, xA1, xB1, t + 5);
        STEP(t + 2, xA3, xB3, xA2, xB2, t + 6);
        STEP(t + 3, xA0, xB0, xA3, xB3, t + 7);
    }
#undef STEP
#undef IHPRE
#undef LOADX

    // ---- dump y: 4096 floats, 16 iterations of (ds_read_b128 + 4 stores) ----
    __syncthreads();  // single wave; orders the last ds_write before reads
    const float4* s_y4 = reinterpret_cast<const float4*>(s_y);
#pragma unroll 4
    for (int it = 0; it < SEQ / 256; ++it) {
        int tbase = it * 256 + lane * 4;
        float4 v = s_y4[tbase >> 2];
        out[(size_t)(tbase + 0) * BATCH + b] = v.x;
        out[(size_t)(tbase + 1) * BATCH + b] = v.y;
        out[(size_t)(tbase + 2) * BATCH + b] = v.z;
        out[(size_t)(tbase + 3) * BATCH + b] = v.w;
    }
}

extern "C" void kernel_launch(void* const* d_in, const int* in_sizes, int n_in,
                              void* d_out, int out_size, void* d_ws, size_t ws_size,
                              hipStream_t stream) {
    const float* x     = (const float*)d_in[0];
    const float* W_ih  = (const float*)d_in[1];
    const float* W_hh  = (const float*)d_in[2];
    const float* b_ih  = (const float*)d_in[3];
    const float* b_hh  = (const float*)d_in[4];
    const float* W_lin = (const float*)d_in[5];
    const float* b_lin = (const float*)d_in[6];
    float* out = (float*)d_out;

    lstm_chain_kernel<<<dim3(BATCH), dim3(64), 0, stream>>>(
        x, W_ih, W_hh, b_ih, b_hh, W_lin, b_lin, out);
}

// Round 10
// 1034.172 us; speedup vs baseline: 1.4467x; 1.4429x over previous
//
#include <hip/hip_runtime.h>

#define SEQ 4096
#define BATCH 512
#define INP 8
#define HID 30
#define LOG2E 1.44269504088896340736f

typedef float f32x2 __attribute__((ext_vector_type(2)));
typedef float f32x4 __attribute__((ext_vector_type(4)));
typedef unsigned uint2v __attribute__((ext_vector_type(2)));

#define RCP(v)  __builtin_amdgcn_rcpf(v)
#if __has_builtin(__builtin_amdgcn_exp2f)
#define EXP2(v) __builtin_amdgcn_exp2f(v)
#else
#define EXP2(v) exp2f(v)
#endif
#define PKFMA(a, b, c) __builtin_elementwise_fma(a, b, c)

// permlane32_swap with both operands = v:
//   returns {lo_rep = [v_lo32 | v_lo32], hi_rep = [v_hi32 | v_hi32]}
__device__ __forceinline__ void rep_halves(float v, float& lo_rep, float& hi_rep) {
#if __has_builtin(__builtin_amdgcn_permlane32_swap)
    uint2v r = __builtin_amdgcn_permlane32_swap(
        __float_as_uint(v), __float_as_uint(v), false, false);
    lo_rep = __uint_as_float(r.x);
    hi_rep = __uint_as_float(r.y);
#else
    float other = __shfl_xor(v, 32, 64);
    bool hi = (threadIdx.x & 32) != 0;
    lo_rep = hi ? other : v;
    hi_rep = hi ? v : other;
#endif
}

template <int CTRL>
__device__ __forceinline__ float dpp_sum_step(float v) {
    return v + __uint_as_float(__builtin_amdgcn_update_dpp(
        0, (int)__float_as_uint(v), CTRL, 0xf, 0xf, true));
}

// Sum within each 32-lane group, pure VALU. Total valid in lanes 15,31,47,63.
__device__ __forceinline__ float group32_reduce(float v) {
    v = dpp_sum_step<0x111>(v);  // row_shr:1
    v = dpp_sum_step<0x112>(v);  // row_shr:2
    v = dpp_sum_step<0x114>(v);  // row_shr:4
    v = dpp_sum_step<0x118>(v);  // row_shr:8
#if __has_builtin(__builtin_amdgcn_permlane16_swap)
    uint2v r = __builtin_amdgcn_permlane16_swap(
        __float_as_uint(v), __float_as_uint(v), false, false);
    return __uint_as_float(r.x) + __uint_as_float(r.y);
#else
    return v + __shfl_xor(v, 16, 64);
#endif
}

// One wave per batch chain (512 waves). The 4096-step recurrence loop is
// VMEM-FREE: x is staged through a double-buffered LDS chunk (64 steps) so
// the only global loads happen once per chunk, and the only vmcnt wait is
// on loads a full chunk (~50k cy) old. Inner x reads are uniform-address
// ds_read_b128 (lgkm, ~120cy, covered by distance-4 rotation). Everything
// else is the proven R7 structure: packed matvec, LDS h-broadcast, DPP
// reduce, s_y LDS buffer, XCD swizzle, exp2-folded weights.
__global__ __launch_bounds__(64)
__attribute__((amdgpu_waves_per_eu(1, 1)))
void lstm_chain_kernel(
    const float* __restrict__ x,     // [SEQ,BATCH,INP]
    const float* __restrict__ W_ih,  // [4H, INP]
    const float* __restrict__ W_hh,  // [4H, HID]
    const float* __restrict__ b_ih,  // [4H]
    const float* __restrict__ b_hh,  // [4H]
    const float* __restrict__ W_lin, // [1, HID]
    const float* __restrict__ b_lin, // [1]
    float* __restrict__ out)         // [SEQ,BATCH,1]
{
    const int lane = threadIdx.x;
    // XCD-aware swizzle: consecutive chains share 64B x-lines / 32B out
    // sectors on one XCD's L2.
    const int g    = blockIdx.x;
    const int b    = (g & 7) * (BATCH / 8) + (g >> 3);
    const int j    = lane & 31;
    const int half = lane >> 5;
    const int jc   = j < HID ? j : HID - 1;
    const int ra   = half * HID + jc;            // i (half0) / f (half1): sigmoid
    const int rb   = 2 * HID + half * HID + jc;  // g (half0, tanh) / o (half1, sigmoid)

    // exp2 folding: sigmoid(v)=rcp(1+2^(-log2e*v)); tanh(v)=1-2*rcp(1+2^(2*log2e*v))
    const float sA   = -LOG2E;
    const float sB   = half ? -LOG2E : 2.0f * LOG2E;
    const float sclB = half ? 1.0f : -2.0f;
    const float addB = half ? 0.0f : 1.0f;
    const float T2L  = 2.0f * LOG2E;  // for tanh(c)

    // ---- packed per-lane weights, pre-scaled, pinned in VGPR pairs ----
    f32x2 wih2_a[INP / 2], wih2_b[INP / 2];
#pragma unroll
    for (int i = 0; i < INP / 2; ++i) {
        f32x2 wa = { W_ih[ra * INP + 2 * i] * sA, W_ih[ra * INP + 2 * i + 1] * sA };
        f32x2 wb = { W_ih[rb * INP + 2 * i] * sB, W_ih[rb * INP + 2 * i + 1] * sB };
        asm volatile("" : "+v"(wa));
        asm volatile("" : "+v"(wb));
        wih2_a[i] = wa;
        wih2_b[i] = wb;
    }
    f32x2 whh2_a[HID / 2], whh2_b[HID / 2];
#pragma unroll
    for (int k = 0; k < HID / 2; ++k) {
        f32x2 wa = { W_hh[ra * HID + 2 * k] * sA, W_hh[ra * HID + 2 * k + 1] * sA };
        f32x2 wb = { W_hh[rb * HID + 2 * k] * sB, W_hh[rb * HID + 2 * k + 1] * sB };
        asm volatile("" : "+v"(wa));
        asm volatile("" : "+v"(wb));
        whh2_a[k] = wa;
        whh2_b[k] = wb;
    }
    const float bias_sa = (b_ih[ra] + b_hh[ra]) * sA;
    const float bias_sb = (b_ih[rb] + b_hh[rb]) * sB;
    const float blin    = b_lin[0];
    const float wlin    = (j < HID) ? W_lin[j] : 0.0f;

    __shared__ float s_y[SEQ];
    __shared__ __align__(16) float s_h[64];          // 0..29 valid; 30..63 dup
    __shared__ __align__(16) float s_x[2 * 64 * INP]; // 2 chunk buffers, 64 steps each

    f32x4* sx4 = reinterpret_cast<f32x4*>(s_x);
    const f32x4* sx4c = reinterpret_cast<const f32x4*>(s_x);

    f32x2 hrf2[HID / 2];
#pragma unroll
    for (int k = 0; k < HID / 2; ++k) hrf2[k] = (f32x2){0.0f, 0.0f};
    float c = 0.0f;

    // ---- chunked x staging ----
    // chunk n (steps 64n..64n+63) lives in LDS buffer (n&1).
    // layout: sx4[buf*128 + step*2 + half], half = 16B of the 32B step row.
    f32x4 stg0, stg1;  // staged data for chunk CH2 (in flight)

#define STAGELOAD(CH2) do {                                                   \
    int _b0 = (CH2) * 64 + (lane >> 1);                                       \
    int _b1 = _b0 + 32;                                                       \
    if (_b0 > SEQ - 1) _b0 = SEQ - 1;                                         \
    if (_b1 > SEQ - 1) _b1 = SEQ - 1;                                         \
    const f32x4* _p0 = (const f32x4*)(x + ((size_t)_b0 * BATCH + b) * INP) + (lane & 1); \
    const f32x4* _p1 = (const f32x4*)(x + ((size_t)_b1 * BATCH + b) * INP) + (lane & 1); \
    stg0 = *_p0;                                                              \
    stg1 = *_p1;                                                              \
} while (0)

#define STAGEWRITE(CHW) do {                                                  \
    f32x4* _d = sx4 + ((CHW) & 1) * 128;                                      \
    _d[lane]      = stg0;                                                     \
    _d[64 + lane] = stg1;                                                     \
} while (0)

// uniform-address LDS read of x for step TL into register pair
#define LOADXL(XA, XB, TL) do {                                               \
    int _e = (((TL) >> 6) & 1) * 128 + ((TL) & 63) * 2;                       \
    XA = sx4c[_e];                                                            \
    XB = sx4c[_e + 1];                                                        \
} while (0)

    // prologue: chunk 0 -> LDS (one vmcnt wait, amortized), chunk 1 in flight
    STAGELOAD(0);
    STAGEWRITE(0);
    STAGELOAD(1);

    f32x4 xA0, xB0, xA1, xB1, xA2, xB2, xA3, xB3;
    LOADXL(xA0, xB0, 0);  LOADXL(xA1, xB1, 1);
    LOADXL(xA2, xB2, 2);  LOADXL(xA3, xB3, 3);

    const f32x4* s_h4 = reinterpret_cast<const f32x4*>(s_h);

#define STEP(T, XA, XB) do {                                                  \
    f32x2 A0 = {bias_sa, 0.0f}, B0 = {bias_sb, 0.0f};                         \
    f32x2 A1 = {0.0f, 0.0f},    B1 = {0.0f, 0.0f};                            \
    f32x2 x01 = __builtin_shufflevector(XA, XA, 0, 1);                        \
    f32x2 x23 = __builtin_shufflevector(XA, XA, 2, 3);                        \
    f32x2 x45 = __builtin_shufflevector(XB, XB, 0, 1);                        \
    f32x2 x67 = __builtin_shufflevector(XB, XB, 2, 3);                        \
    A0 = PKFMA(x01, wih2_a[0], A0);  B0 = PKFMA(x01, wih2_b[0], B0);          \
    A1 = PKFMA(x23, wih2_a[1], A1);  B1 = PKFMA(x23, wih2_b[1], B1);          \
    A0 = PKFMA(x45, wih2_a[2], A0);  B0 = PKFMA(x45, wih2_b[2], B0);          \
    A1 = PKFMA(x67, wih2_a[3], A1);  B1 = PKFMA(x67, wih2_b[3], B1);          \
    _Pragma("unroll")                                                         \
    for (int k = 0; k < HID / 2 - 1; k += 2) {                                \
        A0 = PKFMA(hrf2[k],   whh2_a[k],   A0);                               \
        B0 = PKFMA(hrf2[k],   whh2_b[k],   B0);                               \
        A1 = PKFMA(hrf2[k+1], whh2_a[k+1], A1);                               \
        B1 = PKFMA(hrf2[k+1], whh2_b[k+1], B1);                               \
    }                                                                         \
    A0 = PKFMA(hrf2[HID/2-1], whh2_a[HID/2-1], A0);                           \
    B0 = PKFMA(hrf2[HID/2-1], whh2_b[HID/2-1], B0);                           \
    f32x2 As = A0 + A1;  float ua = As.x + As.y;                              \
    f32x2 Bs = B0 + B1;  float ub = Bs.x + Bs.y;                              \
    float Av  = RCP(1.0f + EXP2(ua));                                         \
    float sBv = RCP(1.0f + EXP2(ub));                                         \
    float Bv  = fmaf(sBv, sclB, addB);                                        \
    float ii, ff, gg, oo;                                                     \
    rep_halves(Av, ii, ff);                                                   \
    rep_halves(Bv, gg, oo);                                                   \
    c = fmaf(ff, c, ii * gg);                                                 \
    float sc = RCP(1.0f + EXP2(c * T2L));                                     \
    float h  = oo * fmaf(sc, -2.0f, 1.0f);                                    \
    s_h[lane] = h;  /* all lanes write; lane 32+j duplicates h_j */           \
    asm volatile("" ::: "memory");  /* keep ds_write before ds_reads */       \
    float p = group32_reduce(h * wlin);                                       \
    if (lane == 31) s_y[T] = p + blin;                                        \
    f32x4 hv0 = s_h4[0], hv1 = s_h4[1], hv2 = s_h4[2], hv3 = s_h4[3];         \
    f32x4 hv4 = s_h4[4], hv5 = s_h4[5], hv6 = s_h4[6], hv7 = s_h4[7];         \
    hrf2[0]  = __builtin_shufflevector(hv0, hv0, 0, 1);                       \
    hrf2[1]  = __builtin_shufflevector(hv0, hv0, 2, 3);                       \
    hrf2[2]  = __builtin_shufflevector(hv1, hv1, 0, 1);                       \
    hrf2[3]  = __builtin_shufflevector(hv1, hv1, 2, 3);                       \
    hrf2[4]  = __builtin_shufflevector(hv2, hv2, 0, 1);                       \
    hrf2[5]  = __builtin_shufflevector(hv2, hv2, 2, 3);                       \
    hrf2[6]  = __builtin_shufflevector(hv3, hv3, 0, 1);                       \
    hrf2[7]  = __builtin_shufflevector(hv3, hv3, 2, 3);                       \
    hrf2[8]  = __builtin_shufflevector(hv4, hv4, 0, 1);                       \
    hrf2[9]  = __builtin_shufflevector(hv4, hv4, 2, 3);                       \
    hrf2[10] = __builtin_shufflevector(hv5, hv5, 0, 1);                       \
    hrf2[11] = __builtin_shufflevector(hv5, hv5, 2, 3);                       \
    hrf2[12] = __builtin_shufflevector(hv6, hv6, 0, 1);                       \
    hrf2[13] = __builtin_shufflevector(hv6, hv6, 2, 3);                       \
    hrf2[14] = __builtin_shufflevector(hv7, hv7, 0, 1);                       \
} while (0)

    for (int ch = 0; ch < SEQ / 64; ++ch) {
        // stg currently holds chunk ch+1 (loaded a full chunk ago -> vmcnt
        // wait is free); write it to its buffer, then launch chunk ch+2.
        STAGEWRITE(ch + 1);
        STAGELOAD(ch + 2);
        const int t0 = ch * 64;
#pragma unroll 1
        for (int tt = 0; tt < 64; tt += 4) {
            const int t = t0 + tt;
            STEP(t + 0, xA0, xB0);  LOADXL(xA0, xB0, t + 4);
            STEP(t + 1, xA1, xB1);  LOADXL(xA1, xB1, t + 5);
            STEP(t + 2, xA2, xB2);  LOADXL(xA2, xB2, t + 6);
            STEP(t + 3, xA3, xB3);  LOADXL(xA3, xB3, t + 7);
        }
    }
#undef STEP
#undef LOADXL
#undef STAGELOAD
#undef STAGEWRITE

    // ---- dump y: 4096 floats, 16 iterations of (ds_read_b128 + 4 stores) ----
    __syncthreads();  // single wave; orders the last ds_write before reads
    const float4* s_y4 = reinterpret_cast<const float4*>(s_y);
#pragma unroll 4
    for (int it = 0; it < SEQ / 256; ++it) {
        int tbase = it * 256 + lane * 4;
        float4 v = s_y4[tbase >> 2];
        out[(size_t)(tbase + 0) * BATCH + b] = v.x;
        out[(size_t)(tbase + 1) * BATCH + b] = v.y;
        out[(size_t)(tbase + 2) * BATCH + b] = v.z;
        out[(size_t)(tbase + 3) * BATCH + b] = v.w;
    }
}

extern "C" void kernel_launch(void* const* d_in, const int* in_sizes, int n_in,
                              void* d_out, int out_size, void* d_ws, size_t ws_size,
                              hipStream_t stream) {
    const float* x     = (const float*)d_in[0];
    const float* W_ih  = (const float*)d_in[1];
    const float* W_hh  = (const float*)d_in[2];
    const float* b_ih  = (const float*)d_in[3];
    const float* b_hh  = (const float*)d_in[4];
    const float* W_lin = (const float*)d_in[5];
    const float* b_lin = (const float*)d_in[6];
    float* out = (float*)d_out;

    lstm_chain_kernel<<<dim3(BATCH), dim3(64), 0, stream>>>(
        x, W_ih, W_hh, b_ih, b_hh, W_lin, b_lin, out);
}

// Round 11
// 945.286 us; speedup vs baseline: 1.5828x; 1.0940x over previous
//
#include <hip/hip_runtime.h>

#define SEQ 4096
#define BATCH 512
#define INP 8
#define HID 30
#define LOG2E 1.44269504088896340736f

typedef float f32x2 __attribute__((ext_vector_type(2)));
typedef float f32x4 __attribute__((ext_vector_type(4)));
typedef unsigned uint2v __attribute__((ext_vector_type(2)));

#define RCP(v)  __builtin_amdgcn_rcpf(v)
#if __has_builtin(__builtin_amdgcn_exp2f)
#define EXP2(v) __builtin_amdgcn_exp2f(v)
#else
#define EXP2(v) exp2f(v)
#endif
#define PKFMA(a, b, c) __builtin_elementwise_fma(a, b, c)

// permlane32_swap with both operands = v:
//   returns {lo_rep = [v_lo32 | v_lo32], hi_rep = [v_hi32 | v_hi32]}
__device__ __forceinline__ void rep_halves(float v, float& lo_rep, float& hi_rep) {
#if __has_builtin(__builtin_amdgcn_permlane32_swap)
    uint2v r = __builtin_amdgcn_permlane32_swap(
        __float_as_uint(v), __float_as_uint(v), false, false);
    lo_rep = __uint_as_float(r.x);
    hi_rep = __uint_as_float(r.y);
#else
    float other = __shfl_xor(v, 32, 64);
    bool hi = (threadIdx.x & 32) != 0;
    lo_rep = hi ? other : v;
    hi_rep = hi ? v : other;
#endif
}

template <int CTRL>
__device__ __forceinline__ float dpp_sum_step(float v) {
    return v + __uint_as_float(__builtin_amdgcn_update_dpp(
        0, (int)__float_as_uint(v), CTRL, 0xf, 0xf, true));
}

// Sum within each 32-lane group, pure VALU. Total valid in lanes 15,31,47,63.
__device__ __forceinline__ float group32_reduce(float v) {
    v = dpp_sum_step<0x111>(v);  // row_shr:1
    v = dpp_sum_step<0x112>(v);  // row_shr:2
    v = dpp_sum_step<0x114>(v);  // row_shr:4
    v = dpp_sum_step<0x118>(v);  // row_shr:8
#if __has_builtin(__builtin_amdgcn_permlane16_swap)
    uint2v r = __builtin_amdgcn_permlane16_swap(
        __float_as_uint(v), __float_as_uint(v), false, false);
    return __uint_as_float(r.x) + __uint_as_float(r.y);
#else
    return v + __shfl_xor(v, 16, 64);
#endif
}

// One wave per batch chain (512 waves). Recurrence loop is VMEM-free (x staged
// through double-buffered LDS chunks of 64 steps). Critical-chain layout:
// h -> ds_write -> 8x ds_read_b128 issued IMMEDIATELY (no clobber; alias
// analysis orders same-address write->read); DPP reduce / s_y / LOADXL /
// next-step ih-pre fill the ~130cy read shadow. B-gate activation carries
// c2 = c*T2L as state (T2L folded into the gate fma) and h = fma(sc,n2o,oo_u)
// -- two muls removed from the serial chain.
__global__ __launch_bounds__(64)
__attribute__((amdgpu_waves_per_eu(1, 1)))
void lstm_chain_kernel(
    const float* __restrict__ x,     // [SEQ,BATCH,INP]
    const float* __restrict__ W_ih,  // [4H, INP]
    const float* __restrict__ W_hh,  // [4H, HID]
    const float* __restrict__ b_ih,  // [4H]
    const float* __restrict__ b_hh,  // [4H]
    const float* __restrict__ W_lin, // [1, HID]
    const float* __restrict__ b_lin, // [1]
    float* __restrict__ out)         // [SEQ,BATCH,1]
{
    const int lane = threadIdx.x;
    // XCD-aware swizzle: consecutive chains share 64B x-lines / 32B out
    // sectors on one XCD's L2.
    const int g    = blockIdx.x;
    const int b    = (g & 7) * (BATCH / 8) + (g >> 3);
    const int j    = lane & 31;
    const int half = lane >> 5;
    const int jc   = j < HID ? j : HID - 1;
    const int ra   = half * HID + jc;            // i (half0) / f (half1): sigmoid
    const int rb   = 2 * HID + half * HID + jc;  // g (half0, tanh) / o (half1, sigmoid)

    // exp2 folding: sigmoid(v)=rcp(1+2^(-log2e*v)); tanh(v)=1-2*rcp(1+2^(2*log2e*v))
    const float sA   = -LOG2E;
    const float sB   = half ? -LOG2E : 2.0f * LOG2E;
    const float T2L  = 2.0f * LOG2E;            // tanh(c) via exp2(c*T2L)
    const float IT2L = 1.0f / (2.0f * LOG2E);
    // B-gate output pre-scaled by T2L: Bv2 = Bv * T2L
    const float sclB2 = half ? T2L : -2.0f * T2L;
    const float addB2 = half ? 0.0f : T2L;

    // ---- packed per-lane weights, pre-scaled, pinned in VGPR pairs ----
    f32x2 wih2_a[INP / 2], wih2_b[INP / 2];
#pragma unroll
    for (int i = 0; i < INP / 2; ++i) {
        f32x2 wa = { W_ih[ra * INP + 2 * i] * sA, W_ih[ra * INP + 2 * i + 1] * sA };
        f32x2 wb = { W_ih[rb * INP + 2 * i] * sB, W_ih[rb * INP + 2 * i + 1] * sB };
        asm volatile("" : "+v"(wa));
        asm volatile("" : "+v"(wb));
        wih2_a[i] = wa;
        wih2_b[i] = wb;
    }
    f32x2 whh2_a[HID / 2], whh2_b[HID / 2];
#pragma unroll
    for (int k = 0; k < HID / 2; ++k) {
        f32x2 wa = { W_hh[ra * HID + 2 * k] * sA, W_hh[ra * HID + 2 * k + 1] * sA };
        f32x2 wb = { W_hh[rb * HID + 2 * k] * sB, W_hh[rb * HID + 2 * k + 1] * sB };
        asm volatile("" : "+v"(wa));
        asm volatile("" : "+v"(wb));
        whh2_a[k] = wa;
        whh2_b[k] = wb;
    }
    const float bias_sa = (b_ih[ra] + b_hh[ra]) * sA;
    const float bias_sb = (b_ih[rb] + b_hh[rb]) * sB;
    const float blin    = b_lin[0];
    const float wlin    = (j < HID) ? W_lin[j] : 0.0f;

    __shared__ float s_y[SEQ];
    __shared__ __align__(16) float s_h[64];           // 0..29 valid; 30..63 dup
    __shared__ __align__(16) float s_x[2 * 64 * INP]; // 2 chunk buffers

    f32x4* sx4 = reinterpret_cast<f32x4*>(s_x);
    const f32x4* sx4c = reinterpret_cast<const f32x4*>(s_x);

    f32x2 hrf2[HID / 2];
#pragma unroll
    for (int k = 0; k < HID / 2; ++k) hrf2[k] = (f32x2){0.0f, 0.0f};
    float c2 = 0.0f;  // carried state: c * T2L

    // ---- chunked x staging (vmcnt waits amortized to once per 64 steps) ----
    f32x4 stg0, stg1;

#define STAGELOAD(CH2) do {                                                   \
    int _b0 = (CH2) * 64 + (lane >> 1);                                       \
    int _b1 = _b0 + 32;                                                       \
    if (_b0 > SEQ - 1) _b0 = SEQ - 1;                                         \
    if (_b1 > SEQ - 1) _b1 = SEQ - 1;                                         \
    const f32x4* _p0 = (const f32x4*)(x + ((size_t)_b0 * BATCH + b) * INP) + (lane & 1); \
    const f32x4* _p1 = (const f32x4*)(x + ((size_t)_b1 * BATCH + b) * INP) + (lane & 1); \
    stg0 = *_p0;                                                              \
    stg1 = *_p1;                                                              \
} while (0)

#define STAGEWRITE(CHW) do {                                                  \
    f32x4* _d = sx4 + ((CHW) & 1) * 128;                                      \
    _d[lane]      = stg0;                                                     \
    _d[64 + lane] = stg1;                                                     \
} while (0)

#define LOADXL(XA, XB, TL) do {                                               \
    int _e = (((TL) >> 6) & 1) * 128 + ((TL) & 63) * 2;                       \
    XA = sx4c[_e];                                                            \
    XB = sx4c[_e + 1];                                                        \
} while (0)

    // rolling pre-activation (bias + W_ih·x) for the NEXT step
    f32x2 preA0, preA1, preB0, preB1;

#define IHPRE(XA, XB) do {                                                    \
    f32x2 x01 = __builtin_shufflevector(XA, XA, 0, 1);                        \
    f32x2 x23 = __builtin_shufflevector(XA, XA, 2, 3);                        \
    f32x2 x45 = __builtin_shufflevector(XB, XB, 0, 1);                        \
    f32x2 x67 = __builtin_shufflevector(XB, XB, 2, 3);                        \
    preA0 = (f32x2){bias_sa, 0.0f};  preB0 = (f32x2){bias_sb, 0.0f};          \
    preA1 = (f32x2){0.0f, 0.0f};     preB1 = (f32x2){0.0f, 0.0f};             \
    preA0 = PKFMA(x01, wih2_a[0], preA0);  preB0 = PKFMA(x01, wih2_b[0], preB0); \
    preA1 = PKFMA(x23, wih2_a[1], preA1);  preB1 = PKFMA(x23, wih2_b[1], preB1); \
    preA0 = PKFMA(x45, wih2_a[2], preA0);  preB0 = PKFMA(x45, wih2_b[2], preB0); \
    preA1 = PKFMA(x67, wih2_a[3], preA1);  preB1 = PKFMA(x67, wih2_b[3], preB1); \
} while (0)

    // prologue
    STAGELOAD(0);
    STAGEWRITE(0);
    STAGELOAD(1);

    f32x4 xA0, xB0, xA1, xB1, xA2, xB2, xA3, xB3;
    LOADXL(xA0, xB0, 0);  LOADXL(xA1, xB1, 1);
    LOADXL(xA2, xB2, 2);  LOADXL(xA3, xB3, 3);
    IHPRE(xA0, xB0);  // pre for t=0

    const f32x4* s_h4 = reinterpret_cast<const f32x4*>(s_h);

// STEP(T, XAn/XBn: slot holding x[T+1] (feeds rolling pre),
//         XAl/XBl: slot to reload with x[TL=T+4])
#define STEP(T, XAn, XBn, XAl, XBl, TL) do {                                  \
    f32x2 A0 = preA0, A1 = preA1, B0 = preB0, B1 = preB1;                     \
    _Pragma("unroll")                                                         \
    for (int k = 0; k < HID / 2 - 1; k += 2) {                                \
        A0 = PKFMA(hrf2[k],   whh2_a[k],   A0);                               \
        B0 = PKFMA(hrf2[k],   whh2_b[k],   B0);                               \
        A1 = PKFMA(hrf2[k+1], whh2_a[k+1], A1);                               \
        B1 = PKFMA(hrf2[k+1], whh2_b[k+1], B1);                               \
    }                                                                         \
    A0 = PKFMA(hrf2[HID/2-1], whh2_a[HID/2-1], A0);                           \
    B0 = PKFMA(hrf2[HID/2-1], whh2_b[HID/2-1], B0);                           \
    f32x2 As = A0 + A1;  float ua = As.x + As.y;                              \
    f32x2 Bs = B0 + B1;  float ub = Bs.x + Bs.y;                              \
    float Av  = RCP(1.0f + EXP2(ua));                                         \
    float sBv = RCP(1.0f + EXP2(ub));                                         \
    float Bv2 = fmaf(sBv, sclB2, addB2);   /* B-gate output scaled by T2L */  \
    float ii, ff, gg2, oT2;                                                   \
    rep_halves(Av,  ii,  ff);                                                 \
    rep_halves(Bv2, gg2, oT2);             /* gg2 = g*T2L, oT2 = o*T2L */     \
    float oo_u = oT2 * IT2L;               /* off-chain */                    \
    float n2o  = oT2 * (-2.0f * IT2L);     /* off-chain */                    \
    c2 = fmaf(ff, c2, ii * gg2);           /* c2 = c*T2L */                   \
    float sc = RCP(1.0f + EXP2(c2));                                          \
    float h  = fmaf(sc, n2o, oo_u);        /* = o * tanh(c) */                \
    s_h[lane] = h;                         /* ds_write */                     \
    f32x4 hv0 = s_h4[0], hv1 = s_h4[1], hv2 = s_h4[2], hv3 = s_h4[3];         \
    f32x4 hv4 = s_h4[4], hv5 = s_h4[5], hv6 = s_h4[6], hv7 = s_h4[7];         \
    /* ---- read shadow: independent work ---- */                             \
    float p = group32_reduce(h * wlin);                                       \
    if (lane == 31) s_y[T] = p + blin;                                        \
    LOADXL(XAl, XBl, TL);                                                     \
    IHPRE(XAn, XBn);                                                          \
    /* ---- unpack broadcast for next step ---- */                            \
    hrf2[0]  = __builtin_shufflevector(hv0, hv0, 0, 1);                       \
    hrf2[1]  = __builtin_shufflevector(hv0, hv0, 2, 3);                       \
    hrf2[2]  = __builtin_shufflevector(hv1, hv1, 0, 1);                       \
    hrf2[3]  = __builtin_shufflevector(hv1, hv1, 2, 3);                       \
    hrf2[4]  = __builtin_shufflevector(hv2, hv2, 0, 1);                       \
    hrf2[5]  = __builtin_shufflevector(hv2, hv2, 2, 3);                       \
    hrf2[6]  = __builtin_shufflevector(hv3, hv3, 0, 1);                       \
    hrf2[7]  = __builtin_shufflevector(hv3, hv3, 2, 3);                       \
    hrf2[8]  = __builtin_shufflevector(hv4, hv4, 0, 1);                       \
    hrf2[9]  = __builtin_shufflevector(hv4, hv4, 2, 3);                       \
    hrf2[10] = __builtin_shufflevector(hv5, hv5, 0, 1);                       \
    hrf2[11] = __builtin_shufflevector(hv5, hv5, 2, 3);                       \
    hrf2[12] = __builtin_shufflevector(hv6, hv6, 0, 1);                       \
    hrf2[13] = __builtin_shufflevector(hv6, hv6, 2, 3);                       \
    hrf2[14] = __builtin_shufflevector(hv7, hv7, 0, 1);                       \
} while (0)

    for (int ch = 0; ch < SEQ / 64; ++ch) {
        STAGEWRITE(ch + 1);
        STAGELOAD(ch + 2);
        const int t0 = ch * 64;
#pragma unroll 1
        for (int tt = 0; tt < 64; tt += 4) {
            const int t = t0 + tt;
            STEP(t + 0, xA1, xB1, xA0, xB0, t + 4);
            STEP(t + 1, xA2, xB2, xA1, xB1, t + 5);
            STEP(t + 2, xA3, xB3, xA2, xB2, t + 6);
            STEP(t + 3, xA0, xB0, xA3, xB3, t + 7);
        }
    }
#undef STEP
#undef IHPRE
#undef LOADXL
#undef STAGELOAD
#undef STAGEWRITE

    // ---- dump y: 4096 floats, 16 iterations of (ds_read_b128 + 4 stores) ----
    __syncthreads();  // single wave; orders the last ds_write before reads
    const float4* s_y4 = reinterpret_cast<const float4*>(s_y);
#pragma unroll 4
    for (int it = 0; it < SEQ / 256; ++it) {
        int tbase = it * 256 + lane * 4;
        float4 v = s_y4[tbase >> 2];
        out[(size_t)(tbase + 0) * BATCH + b] = v.x;
        out[(size_t)(tbase + 1) * BATCH + b] = v.y;
        out[(size_t)(tbase + 2) * BATCH + b] = v.z;
        out[(size_t)(tbase + 3) * BATCH + b] = v.w;
    }
}

extern "C" void kernel_launch(void* const* d_in, const int* in_sizes, int n_in,
                              void* d_out, int out_size, void* d_ws, size_t ws_size,
                              hipStream_t stream) {
    const float* x     = (const float*)d_in[0];
    const float* W_ih  = (const float*)d_in[1];
    const float* W_hh  = (const float*)d_in[2];
    const float* b_ih  = (const float*)d_in[3];
    const float* b_hh  = (const float*)d_in[4];
    const float* W_lin = (const float*)d_in[5];
    const float* b_lin = (const float*)d_in[6];
    float* out = (float*)d_out;

    lstm_chain_kernel<<<dim3(BATCH), dim3(64), 0, stream>>>(
        x, W_ih, W_hh, b_ih, b_hh, W_lin, b_lin, out);
}